// Round 1
// baseline (739.687 us; speedup 1.0000x reference)
//
#include <hip/hip_runtime.h>
#include <hip/hip_bf16.h>

#define Bb 32
#define Ss 512
#define Ee 512
#define Hh 8
#define Dd 64
#define EPSf 1e-5f

typedef __attribute__((ext_vector_type(8))) unsigned short ushort8_t;
typedef __attribute__((ext_vector_type(4))) unsigned short ushort4_t;

__device__ __forceinline__ float bf2f(unsigned short u) {
  union { unsigned int i; float f; } x;
  x.i = ((unsigned int)u) << 16;
  return x.f;
}

// ---------------- QKV projection GEMM ----------------
// C[m][n] = sum_k X[m][k]*Win[n][k] + bin[n]; M=16384, N=1536, K=512
// scatter to Q/K/V bf16 laid out [B*H][S][D]
__global__ __launch_bounds__(256) void qkv_gemm(
    const float* __restrict__ X, const float* __restrict__ Win,
    const float* __restrict__ bin,
    __hip_bfloat16* __restrict__ Qo, __hip_bfloat16* __restrict__ Ko,
    __hip_bfloat16* __restrict__ Vo) {
  __shared__ float As[16][132];
  __shared__ float Bs[16][132];
  const int tid = threadIdx.x;
  const int tx = tid & 15, ty = tid >> 4;
  const int m0 = blockIdx.y * 128, n0 = blockIdx.x * 128;
  float c[8][8];
#pragma unroll
  for (int i = 0; i < 8; ++i)
#pragma unroll
    for (int j = 0; j < 8; ++j) c[i][j] = 0.f;

  for (int k0 = 0; k0 < 512; k0 += 16) {
#pragma unroll
    for (int r = 0; r < 2; ++r) {
      int idx = tid + r * 256;
      int row = idx >> 2, kq = (idx & 3) * 4;
      float4 va = *(const float4*)(X + (size_t)(m0 + row) * 512 + k0 + kq);
      float4 vb = *(const float4*)(Win + (size_t)(n0 + row) * 512 + k0 + kq);
      As[kq + 0][row] = va.x; As[kq + 1][row] = va.y;
      As[kq + 2][row] = va.z; As[kq + 3][row] = va.w;
      Bs[kq + 0][row] = vb.x; Bs[kq + 1][row] = vb.y;
      Bs[kq + 2][row] = vb.z; Bs[kq + 3][row] = vb.w;
    }
    __syncthreads();
#pragma unroll
    for (int kk = 0; kk < 16; ++kk) {
      float a[8], bv[8];
      *(float4*)&a[0] = *(const float4*)&As[kk][ty * 8];
      *(float4*)&a[4] = *(const float4*)&As[kk][ty * 8 + 4];
      *(float4*)&bv[0] = *(const float4*)&Bs[kk][tx * 8];
      *(float4*)&bv[4] = *(const float4*)&Bs[kk][tx * 8 + 4];
#pragma unroll
      for (int i = 0; i < 8; ++i)
#pragma unroll
        for (int j = 0; j < 8; ++j) c[i][j] += a[i] * bv[j];
    }
    __syncthreads();
  }
#pragma unroll
  for (int i = 0; i < 8; ++i) {
    int m = m0 + ty * 8 + i;
    int bb = m >> 9, ss = m & 511;
#pragma unroll
    for (int j = 0; j < 8; ++j) {
      int n = n0 + tx * 8 + j;
      float val = c[i][j] + bin[n];
      int which = n >> 9, e = n & 511;
      int h = e >> 6, d = e & 63;
      __hip_bfloat16* dst = (which == 0) ? Qo : (which == 1) ? Ko : Vo;
      dst[((size_t)(bb * Hh + h) * Ss + ss) * Dd + d] = __float2bfloat16(val);
    }
  }
}

// ---------------- score GEMM ----------------
// per (b,h): raw[m][n] = 0.125 * sum_d Q[m][d]*K[n][d]; written to att region
__global__ __launch_bounds__(256) void score_gemm(
    const __hip_bfloat16* __restrict__ Q, const __hip_bfloat16* __restrict__ Kb,
    float* __restrict__ att) {
  __shared__ float As[16][132];
  __shared__ float Bs[16][132];
  const int tid = threadIdx.x;
  const int tx = tid & 15, ty = tid >> 4;
  const int bh = blockIdx.z;
  const int m0 = blockIdx.y * 128, n0 = blockIdx.x * 128;
  const unsigned short* Qp = (const unsigned short*)Q + (size_t)bh * Ss * Dd;
  const unsigned short* Kp = (const unsigned short*)Kb + (size_t)bh * Ss * Dd;
  float c[8][8];
#pragma unroll
  for (int i = 0; i < 8; ++i)
#pragma unroll
    for (int j = 0; j < 8; ++j) c[i][j] = 0.f;

  for (int k0 = 0; k0 < 64; k0 += 16) {
    int row = tid >> 1, half = (tid & 1) * 8;
    ushort8_t ua = *(const ushort8_t*)(Qp + (size_t)(m0 + row) * Dd + k0 + half);
    ushort8_t ub = *(const ushort8_t*)(Kp + (size_t)(n0 + row) * Dd + k0 + half);
#pragma unroll
    for (int cc = 0; cc < 8; ++cc) {
      As[half + cc][row] = bf2f(ua[cc]);
      Bs[half + cc][row] = bf2f(ub[cc]);
    }
    __syncthreads();
#pragma unroll
    for (int kk = 0; kk < 16; ++kk) {
      float a[8], bv[8];
      *(float4*)&a[0] = *(const float4*)&As[kk][ty * 8];
      *(float4*)&a[4] = *(const float4*)&As[kk][ty * 8 + 4];
      *(float4*)&bv[0] = *(const float4*)&Bs[kk][tx * 8];
      *(float4*)&bv[4] = *(const float4*)&Bs[kk][tx * 8 + 4];
#pragma unroll
      for (int i = 0; i < 8; ++i)
#pragma unroll
        for (int j = 0; j < 8; ++j) c[i][j] += a[i] * bv[j];
    }
    __syncthreads();
  }
  float* out = att + (size_t)bh * Ss * Ss;
#pragma unroll
  for (int i = 0; i < 8; ++i) {
    int m = m0 + ty * 8 + i;
    float4 lo, hi;
    lo.x = c[i][0] * 0.125f; lo.y = c[i][1] * 0.125f;
    lo.z = c[i][2] * 0.125f; lo.w = c[i][3] * 0.125f;
    hi.x = c[i][4] * 0.125f; hi.y = c[i][5] * 0.125f;
    hi.z = c[i][6] * 0.125f; hi.w = c[i][7] * 0.125f;
    *(float4*)(out + (size_t)m * Ss + n0 + tx * 8) = lo;
    *(float4*)(out + (size_t)m * Ss + n0 + tx * 8 + 4) = hi;
  }
}

// ---------------- row softmax (in place) ----------------
// 131072 rows of 512. block = 256 (4 waves), each wave handles 8 rows.
__global__ __launch_bounds__(256) void softmax_rows(float* __restrict__ att) {
  const int wave = threadIdx.x >> 6, lane = threadIdx.x & 63;
  for (int r = 0; r < 8; ++r) {
    size_t row = (size_t)blockIdx.x * 32 + wave * 8 + r;
    float* p = att + row * Ss;
    float4 v0 = ((float4*)p)[lane];
    float4 v1 = ((float4*)p)[lane + 64];
    float m = fmaxf(fmaxf(fmaxf(v0.x, v0.y), fmaxf(v0.z, v0.w)),
                    fmaxf(fmaxf(v1.x, v1.y), fmaxf(v1.z, v1.w)));
#pragma unroll
    for (int off = 32; off; off >>= 1) m = fmaxf(m, __shfl_xor(m, off));
    v0.x = __expf(v0.x - m); v0.y = __expf(v0.y - m);
    v0.z = __expf(v0.z - m); v0.w = __expf(v0.w - m);
    v1.x = __expf(v1.x - m); v1.y = __expf(v1.y - m);
    v1.z = __expf(v1.z - m); v1.w = __expf(v1.w - m);
    float s = v0.x + v0.y + v0.z + v0.w + v1.x + v1.y + v1.z + v1.w;
#pragma unroll
    for (int off = 32; off; off >>= 1) s += __shfl_xor(s, off);
    float inv = 1.0f / s;
    v0.x *= inv; v0.y *= inv; v0.z *= inv; v0.w *= inv;
    v1.x *= inv; v1.y *= inv; v1.z *= inv; v1.w *= inv;
    ((float4*)p)[lane] = v0;
    ((float4*)p)[lane + 64] = v1;
  }
}

// ---------------- PV GEMM ----------------
// per (b,h): Z[b][m][h*64+n] = sum_k P[m][k] * V[k][n]; tile 128x64
__global__ __launch_bounds__(256) void pv_gemm(
    const float* __restrict__ att, const __hip_bfloat16* __restrict__ Vb,
    float* __restrict__ Z) {
  __shared__ float As[16][132];
  __shared__ float Bs[16][68];
  const int tid = threadIdx.x;
  const int tx = tid & 15, ty = tid >> 4;
  const int bh = blockIdx.z;
  const int b = bh >> 3, h = bh & 7;
  const int m0 = blockIdx.y * 128;
  const float* P = att + (size_t)bh * Ss * Ss;
  const unsigned short* Vp = (const unsigned short*)Vb + (size_t)bh * Ss * Dd;
  float c[8][4];
#pragma unroll
  for (int i = 0; i < 8; ++i)
#pragma unroll
    for (int j = 0; j < 4; ++j) c[i][j] = 0.f;

  for (int k0 = 0; k0 < 512; k0 += 16) {
#pragma unroll
    for (int r = 0; r < 2; ++r) {
      int idx = tid + r * 256;
      int row = idx >> 2, kq = (idx & 3) * 4;
      float4 va = *(const float4*)(P + (size_t)(m0 + row) * Ss + k0 + kq);
      As[kq + 0][row] = va.x; As[kq + 1][row] = va.y;
      As[kq + 2][row] = va.z; As[kq + 3][row] = va.w;
    }
    {
      int kk = tid >> 4, n4 = (tid & 15) * 4;
      ushort4_t uv = *(const ushort4_t*)(Vp + (size_t)(k0 + kk) * Dd + n4);
      Bs[kk][n4 + 0] = bf2f(uv[0]); Bs[kk][n4 + 1] = bf2f(uv[1]);
      Bs[kk][n4 + 2] = bf2f(uv[2]); Bs[kk][n4 + 3] = bf2f(uv[3]);
    }
    __syncthreads();
#pragma unroll
    for (int kk = 0; kk < 16; ++kk) {
      float a[8], bv[4];
      *(float4*)&a[0] = *(const float4*)&As[kk][ty * 8];
      *(float4*)&a[4] = *(const float4*)&As[kk][ty * 8 + 4];
      *(float4*)&bv[0] = *(const float4*)&Bs[kk][tx * 4];
#pragma unroll
      for (int i = 0; i < 8; ++i)
#pragma unroll
        for (int j = 0; j < 4; ++j) c[i][j] += a[i] * bv[j];
    }
    __syncthreads();
  }
#pragma unroll
  for (int i = 0; i < 8; ++i) {
    int m = m0 + ty * 8 + i;
    float4 o;
    o.x = c[i][0]; o.y = c[i][1]; o.z = c[i][2]; o.w = c[i][3];
    *(float4*)(Z + ((size_t)(b * Ss + m) * Ee) + h * Dd + tx * 4) = o;
  }
}

// ---------------- out projection GEMM ----------------
// C[m][n] = sum_k Z[m][k]*Wout[n][k] + bout[n] + X[m][n]; M=16384,N=512,K=512
__global__ __launch_bounds__(256) void out_gemm(
    const float* __restrict__ Z, const float* __restrict__ Wout,
    const float* __restrict__ bout, const float* __restrict__ X,
    float* __restrict__ Z2) {
  __shared__ float As[16][132];
  __shared__ float Bs[16][132];
  const int tid = threadIdx.x;
  const int tx = tid & 15, ty = tid >> 4;
  const int m0 = blockIdx.y * 128, n0 = blockIdx.x * 128;
  float c[8][8];
#pragma unroll
  for (int i = 0; i < 8; ++i)
#pragma unroll
    for (int j = 0; j < 8; ++j) c[i][j] = 0.f;

  for (int k0 = 0; k0 < 512; k0 += 16) {
#pragma unroll
    for (int r = 0; r < 2; ++r) {
      int idx = tid + r * 256;
      int row = idx >> 2, kq = (idx & 3) * 4;
      float4 va = *(const float4*)(Z + (size_t)(m0 + row) * 512 + k0 + kq);
      float4 vb = *(const float4*)(Wout + (size_t)(n0 + row) * 512 + k0 + kq);
      As[kq + 0][row] = va.x; As[kq + 1][row] = va.y;
      As[kq + 2][row] = va.z; As[kq + 3][row] = va.w;
      Bs[kq + 0][row] = vb.x; Bs[kq + 1][row] = vb.y;
      Bs[kq + 2][row] = vb.z; Bs[kq + 3][row] = vb.w;
    }
    __syncthreads();
#pragma unroll
    for (int kk = 0; kk < 16; ++kk) {
      float a[8], bv[8];
      *(float4*)&a[0] = *(const float4*)&As[kk][ty * 8];
      *(float4*)&a[4] = *(const float4*)&As[kk][ty * 8 + 4];
      *(float4*)&bv[0] = *(const float4*)&Bs[kk][tx * 8];
      *(float4*)&bv[4] = *(const float4*)&Bs[kk][tx * 8 + 4];
#pragma unroll
      for (int i = 0; i < 8; ++i)
#pragma unroll
        for (int j = 0; j < 8; ++j) c[i][j] += a[i] * bv[j];
    }
    __syncthreads();
  }
  const float4 bo0 = *(const float4*)(bout + n0 + tx * 8);
  const float4 bo1 = *(const float4*)(bout + n0 + tx * 8 + 4);
#pragma unroll
  for (int i = 0; i < 8; ++i) {
    int m = m0 + ty * 8 + i;
    const float4 x0 = *(const float4*)(X + (size_t)m * 512 + n0 + tx * 8);
    const float4 x1 = *(const float4*)(X + (size_t)m * 512 + n0 + tx * 8 + 4);
    float4 o0, o1;
    o0.x = c[i][0] + bo0.x + x0.x; o0.y = c[i][1] + bo0.y + x0.y;
    o0.z = c[i][2] + bo0.z + x0.z; o0.w = c[i][3] + bo0.w + x0.w;
    o1.x = c[i][4] + bo1.x + x1.x; o1.y = c[i][5] + bo1.y + x1.y;
    o1.z = c[i][6] + bo1.z + x1.z; o1.w = c[i][7] + bo1.w + x1.w;
    *(float4*)(Z2 + (size_t)m * 512 + n0 + tx * 8) = o0;
    *(float4*)(Z2 + (size_t)m * 512 + n0 + tx * 8 + 4) = o1;
  }
}

// ---------------- LayerNorm (in place on y region) ----------------
__global__ __launch_bounds__(128) void ln_kernel(
    const float* __restrict__ Z2, const float* __restrict__ gamma,
    const float* __restrict__ beta, float* __restrict__ Y) {
  const int row = blockIdx.x;
  const int t = threadIdx.x;
  float4 v = *(const float4*)(Z2 + (size_t)row * 512 + t * 4);
  float sum = v.x + v.y + v.z + v.w;
  float sq = v.x * v.x + v.y * v.y + v.z * v.z + v.w * v.w;
#pragma unroll
  for (int off = 32; off; off >>= 1) {
    sum += __shfl_xor(sum, off);
    sq += __shfl_xor(sq, off);
  }
  __shared__ float s0[2], s1[2];
  int wv = t >> 6;
  if ((t & 63) == 0) { s0[wv] = sum; s1[wv] = sq; }
  __syncthreads();
  sum = s0[0] + s0[1];
  sq = s1[0] + s1[1];
  float mu = sum * (1.0f / 512.0f);
  float var = sq * (1.0f / 512.0f) - mu * mu;
  float rs = rsqrtf(var + EPSf);
  float4 g = *(const float4*)(gamma + t * 4);
  float4 be = *(const float4*)(beta + t * 4);
  float4 o;
  o.x = (v.x - mu) * rs * g.x + be.x;
  o.y = (v.y - mu) * rs * g.y + be.y;
  o.z = (v.z - mu) * rs * g.z + be.z;
  o.w = (v.w - mu) * rs * g.w + be.w;
  *(float4*)(Y + (size_t)row * 512 + t * 4) = o;
}

extern "C" void kernel_launch(void* const* d_in, const int* in_sizes, int n_in,
                              void* d_out, int out_size, void* d_ws, size_t ws_size,
                              hipStream_t stream) {
  const float* x = (const float*)d_in[0];
  const float* w_in = (const float*)d_in[1];
  const float* b_in = (const float*)d_in[2];
  const float* w_out = (const float*)d_in[3];
  const float* b_out = (const float*)d_in[4];
  const float* gamma = (const float*)d_in[5];
  const float* beta = (const float*)d_in[6];

  float* y = (float*)d_out;                              // [B,S,E] fp32
  float* att = (float*)d_out + (size_t)Bb * Ss * Ee;     // [B,H,S,S] fp32

  char* ws = (char*)d_ws;
  const size_t QKV_BYTES = (size_t)Bb * Hh * Ss * Dd * sizeof(__hip_bfloat16); // 16.78 MB
  __hip_bfloat16* Q = (__hip_bfloat16*)ws;
  __hip_bfloat16* Kb = (__hip_bfloat16*)(ws + QKV_BYTES);
  __hip_bfloat16* Vb = (__hip_bfloat16*)(ws + 2 * QKV_BYTES);
  float* Z = (float*)(ws + 3 * QKV_BYTES);               // [B,S,E] fp32 (33.5 MB)

  // 1) QKV projection
  qkv_gemm<<<dim3(12, 128), 256, 0, stream>>>(x, w_in, b_in, Q, Kb, Vb);
  // 2) raw scores into att region of d_out
  score_gemm<<<dim3(4, 4, 256), 256, 0, stream>>>(Q, Kb, att);
  // 3) softmax in place -> final att_w
  softmax_rows<<<dim3(4096), 256, 0, stream>>>(att);
  // 4) PV -> Z (heads merged)
  pv_gemm<<<dim3(1, 4, 256), 256, 0, stream>>>(att, Vb, Z);
  // 5) out projection + bias + residual -> y region (pre-LN values)
  out_gemm<<<dim3(4, 128), 256, 0, stream>>>(Z, w_out, b_out, x, y);
  // 6) LayerNorm in place on y region
  ln_kernel<<<dim3(16384), 128, 0, stream>>>(y, gamma, beta, y);
}

// Round 2
// 267.714 us; speedup vs baseline: 2.7630x; 2.7630x over previous
//
#include <hip/hip_runtime.h>
#include <hip/hip_bf16.h>
#include <stdint.h>

#define Bb 32
#define Ss 512
#define Ee 512
#define Hh 8
#define Dd 64
#define EPSf 1e-5f

typedef __attribute__((ext_vector_type(8))) unsigned short ushort8_t;
typedef __attribute__((ext_vector_type(4))) float f32x4;
typedef __attribute__((ext_vector_type(8))) __bf16 bf16x8;

union U8cast { ushort8_t u; bf16x8 b; };
__device__ __forceinline__ bf16x8 as_bf16x8(ushort8_t u) { U8cast c; c.u = u; return c.b; }

__device__ __forceinline__ unsigned short f2bf(float f) {
  __bf16 b = (__bf16)f;                 // RNE fptrunc
  return __builtin_bit_cast(unsigned short, b);
}

__device__ __forceinline__ f32x4 mfma16(bf16x8 a, bf16x8 b, f32x4 c) {
  return __builtin_amdgcn_mfma_f32_16x16x32_bf16(a, b, c, 0, 0, 0);
}

__device__ __forceinline__ void async16(const unsigned short* g, unsigned short* l) {
  __builtin_amdgcn_global_load_lds(
      (const __attribute__((address_space(1))) void*)g,
      (__attribute__((address_space(3))) void*)l, 16, 0, 0);
}

// ---------------- fp32 -> bf16 convert ----------------
__global__ __launch_bounds__(256) void cvt_bf16(const float* __restrict__ src,
                                                unsigned short* __restrict__ dst, int n8) {
  int i = blockIdx.x * 256 + threadIdx.x;
  int stride = gridDim.x * 256;
  for (; i < n8; i += stride) {
    float4 v0 = ((const float4*)src)[2 * i];
    float4 v1 = ((const float4*)src)[2 * i + 1];
    ushort8_t o;
    o[0] = f2bf(v0.x); o[1] = f2bf(v0.y); o[2] = f2bf(v0.z); o[3] = f2bf(v0.w);
    o[4] = f2bf(v1.x); o[5] = f2bf(v1.y); o[6] = f2bf(v1.z); o[7] = f2bf(v1.w);
    ((ushort8_t*)dst)[i] = o;
  }
}

// ---------------- QKV projection: MFMA bf16 ----------------
// C[m][n] = sum_k Xb[m][k] * Wb[n][k] + bin[n];  M=16384, N=1536, K=512
// scatter to Q/K/V bf16 [B*H][S][D]
__global__ __launch_bounds__(256) void qkv_mm(
    const unsigned short* __restrict__ Xb, const unsigned short* __restrict__ Wb,
    const float* __restrict__ bin,
    unsigned short* __restrict__ Qo, unsigned short* __restrict__ Ko,
    unsigned short* __restrict__ Vo) {
  __shared__ unsigned short As[128 * 64];
  __shared__ unsigned short Bs[128 * 64];
  const int tid = threadIdx.x;
  const int w = tid >> 6, l = tid & 63;
  const int lr = l & 15, lg = l >> 4;
  const int m0 = blockIdx.y * 128, n0 = blockIdx.x * 128;
  const int wm = (w >> 1) * 64, wn = (w & 1) * 64;
  f32x4 acc[4][4];
#pragma unroll
  for (int i = 0; i < 4; ++i)
#pragma unroll
    for (int j = 0; j < 4; ++j) acc[i][j] = (f32x4){0.f, 0.f, 0.f, 0.f};

  for (int k0 = 0; k0 < 512; k0 += 64) {
    // stage 128x64 A and B tiles; source pre-swizzled so LDS stays linear (G21)
#pragma unroll
    for (int i = 0; i < 4; ++i) {
      int ci = (w * 4 + i) * 64 + l;         // 16B-chunk index
      int row = ci >> 3, kc = ci & 7;
      int gkc = kc ^ (row & 7);
      async16(Xb + (size_t)(m0 + row) * 512 + k0 + gkc * 8, &As[(w * 4 + i) * 512]);
      async16(Wb + (size_t)(n0 + row) * 512 + k0 + gkc * 8, &Bs[(w * 4 + i) * 512]);
    }
    __syncthreads();
#pragma unroll
    for (int ks = 0; ks < 2; ++ks) {
      bf16x8 af[4], bfr[4];
#pragma unroll
      for (int mf = 0; mf < 4; ++mf) {
        int row = wm + mf * 16 + lr;
        int gc = ks * 4 + lg;
        af[mf] = as_bf16x8(*(const ushort8_t*)&As[row * 64 + ((gc ^ (row & 7)) * 8)]);
      }
#pragma unroll
      for (int nf = 0; nf < 4; ++nf) {
        int row = wn + nf * 16 + lr;
        int gc = ks * 4 + lg;
        bfr[nf] = as_bf16x8(*(const ushort8_t*)&Bs[row * 64 + ((gc ^ (row & 7)) * 8)]);
      }
#pragma unroll
      for (int mf = 0; mf < 4; ++mf)
#pragma unroll
        for (int nf = 0; nf < 4; ++nf) acc[mf][nf] = mfma16(af[mf], bfr[nf], acc[mf][nf]);
    }
    __syncthreads();
  }

#pragma unroll
  for (int nf = 0; nf < 4; ++nf) {
    int n = n0 + wn + nf * 16 + lr;
    float bias = bin[n];
    int which = n >> 9, e = n & 511, h = e >> 6, d = e & 63;
    unsigned short* dst = (which == 0) ? Qo : (which == 1) ? Ko : Vo;
#pragma unroll
    for (int mf = 0; mf < 4; ++mf) {
#pragma unroll
      for (int r = 0; r < 4; ++r) {
        int m = m0 + wm + mf * 16 + lg * 4 + r;
        int bb = m >> 9, s = m & 511;
        dst[(((size_t)(bb * Hh + h)) * Ss + s) * Dd + d] = f2bf(acc[mf][nf][r] + bias);
      }
    }
  }
}

// ---------------- fused attention ----------------
// block: one (b,h), 64 q-rows; 4 waves x 16 q-rows each.
// scores in registers (32 frags), wave-local softmax, att written once,
// P->LDS bf16 (swizzled) -> PV MFMA vs LDS-transposed V. Z out as bf16.
__global__ __launch_bounds__(256) void attn_fused(
    const unsigned short* __restrict__ Q, const unsigned short* __restrict__ K,
    const unsigned short* __restrict__ V, float* __restrict__ att,
    unsigned short* __restrict__ Zb) {
  __shared__ unsigned short smem[40960];   // Vt 32768 (64KB) + P 4x2048 (16KB)
  unsigned short* Vt = smem;
  const int tid = threadIdx.x;
  const int w = tid >> 6, l = tid & 63;
  const int lr = l & 15, lg = l >> 4;
  const int bh = blockIdx.y;
  const int b = bh >> 3, h = bh & 7;
  const int m0 = blockIdx.x * 64;
  const unsigned short* Qp = Q + (size_t)bh * Ss * Dd;
  const unsigned short* Kp = K + (size_t)bh * Ss * Dd;
  const unsigned short* Vp = V + (size_t)bh * Ss * Dd;

  // ---- V transpose into LDS: Vt[d][k], 16B chunks XOR-swizzled by (d&7)
#pragma unroll
  for (int it = 0; it < 16; ++it) {
    int k = it * 32 + (tid >> 3);
    int d0 = (tid & 7) * 8;
    ushort8_t v = *(const ushort8_t*)(Vp + (size_t)k * 64 + d0);
#pragma unroll
    for (int i = 0; i < 8; ++i) {
      int d = d0 + i;
      Vt[d * 512 + (((k >> 3) ^ (d & 7)) * 8) + (k & 7)] = v[i];
    }
  }

  // ---- Q fragments (row = lr, k = lg*8+j), two k-halves of D=64
  const int q0g = m0 + w * 16;
  bf16x8 aq0 = as_bf16x8(*(const ushort8_t*)(Qp + (size_t)(q0g + lr) * Dd + lg * 8));
  bf16x8 aq1 = as_bf16x8(*(const ushort8_t*)(Qp + (size_t)(q0g + lr) * Dd + 32 + lg * 8));

  __syncthreads();   // Vt ready

  // ---- scores: 32 n-fragments across all 512 keys
  f32x4 sc[32];
#pragma unroll
  for (int nf = 0; nf < 32; ++nf) {
    int n = nf * 16 + lr;
    bf16x8 bk0 = as_bf16x8(*(const ushort8_t*)(Kp + (size_t)n * Dd + lg * 8));
    bf16x8 bk1 = as_bf16x8(*(const ushort8_t*)(Kp + (size_t)n * Dd + 32 + lg * 8));
    f32x4 z = (f32x4){0.f, 0.f, 0.f, 0.f};
    z = mfma16(aq0, bk0, z);
    sc[nf] = mfma16(aq1, bk1, z);
  }

  // ---- softmax over keys (row = q lives on (lg,r); cols spread over 16 lanes)
#pragma unroll
  for (int r = 0; r < 4; ++r) {
    float m = sc[0][r];
#pragma unroll
    for (int nf = 1; nf < 32; ++nf) m = fmaxf(m, sc[nf][r]);
    m = fmaxf(m, __shfl_xor(m, 1));
    m = fmaxf(m, __shfl_xor(m, 2));
    m = fmaxf(m, __shfl_xor(m, 4));
    m = fmaxf(m, __shfl_xor(m, 8));
    float ssum = 0.f;
#pragma unroll
    for (int nf = 0; nf < 32; ++nf) {
      float p = __expf((sc[nf][r] - m) * 0.125f);
      sc[nf][r] = p;
      ssum += p;
    }
    ssum += __shfl_xor(ssum, 1);
    ssum += __shfl_xor(ssum, 2);
    ssum += __shfl_xor(ssum, 4);
    ssum += __shfl_xor(ssum, 8);
    float inv = 1.0f / ssum;
#pragma unroll
    for (int nf = 0; nf < 32; ++nf) sc[nf][r] *= inv;
  }

  // ---- write final att_w (only pass over the 268MB output)
  float* attp = att + (size_t)bh * Ss * Ss;
#pragma unroll
  for (int nf = 0; nf < 32; ++nf) {
#pragma unroll
    for (int r = 0; r < 4; ++r) {
      int q = q0g + lg * 4 + r;
      attp[(size_t)q * Ss + nf * 16 + lr] = sc[nf][r];
    }
  }

  // ---- PV in 4 chunks of 128 keys, P staged per-wave in LDS (swizzled)
  unsigned short* Pl = smem + 32768 + w * 2048;   // [16][128] bf16
  f32x4 o[4];
#pragma unroll
  for (int df = 0; df < 4; ++df) o[df] = (f32x4){0.f, 0.f, 0.f, 0.f};
#pragma unroll
  for (int c = 0; c < 4; ++c) {
#pragma unroll
    for (int j = 0; j < 8; ++j) {
      int nf = c * 8 + j;
      int kk = j * 16 + lr;                       // k index within chunk
#pragma unroll
      for (int r = 0; r < 4; ++r) {
        int q = lg * 4 + r;
        Pl[q * 128 + (((kk >> 3) ^ (q & 7)) * 8) + (kk & 7)] = f2bf(sc[nf][r]);
      }
    }
#pragma unroll
    for (int kk = 0; kk < 4; ++kk) {
      bf16x8 ap = as_bf16x8(*(const ushort8_t*)&Pl[lr * 128 + (((kk * 4 + lg) ^ (lr & 7)) * 8)]);
#pragma unroll
      for (int df = 0; df < 4; ++df) {
        int d = df * 16 + lr;
        int gkc = c * 16 + kk * 4 + lg;
        bf16x8 bv = as_bf16x8(*(const ushort8_t*)&Vt[d * 512 + ((gkc ^ (d & 7)) * 8)]);
        o[df] = mfma16(ap, bv, o[df]);
      }
    }
  }

  // ---- Z (merged heads) as bf16 for the out-projection
#pragma unroll
  for (int df = 0; df < 4; ++df) {
#pragma unroll
    for (int r = 0; r < 4; ++r) {
      int q = q0g + lg * 4 + r;
      int d = h * Dd + df * 16 + lr;
      Zb[((size_t)(b * Ss + q)) * Ee + d] = f2bf(o[df][r]);
    }
  }
}

// ---------------- out projection: MFMA bf16 + bias + residual ----------------
// y[m][n] = sum_k Zb[m][k]*Wout[n][k] + bout[n] + X[m][n]; M=16384, N=512, K=512
__global__ __launch_bounds__(256) void out_mm(
    const unsigned short* __restrict__ Zb, const unsigned short* __restrict__ Wb,
    const float* __restrict__ bout, const float* __restrict__ X,
    float* __restrict__ Y) {
  __shared__ unsigned short As[128 * 64];
  __shared__ unsigned short Bs[128 * 64];
  const int tid = threadIdx.x;
  const int w = tid >> 6, l = tid & 63;
  const int lr = l & 15, lg = l >> 4;
  const int m0 = blockIdx.y * 128, n0 = blockIdx.x * 128;
  const int wm = (w >> 1) * 64, wn = (w & 1) * 64;
  f32x4 acc[4][4];
#pragma unroll
  for (int i = 0; i < 4; ++i)
#pragma unroll
    for (int j = 0; j < 4; ++j) acc[i][j] = (f32x4){0.f, 0.f, 0.f, 0.f};

  for (int k0 = 0; k0 < 512; k0 += 64) {
#pragma unroll
    for (int i = 0; i < 4; ++i) {
      int ci = (w * 4 + i) * 64 + l;
      int row = ci >> 3, kc = ci & 7;
      int gkc = kc ^ (row & 7);
      async16(Zb + (size_t)(m0 + row) * 512 + k0 + gkc * 8, &As[(w * 4 + i) * 512]);
      async16(Wb + (size_t)(n0 + row) * 512 + k0 + gkc * 8, &Bs[(w * 4 + i) * 512]);
    }
    __syncthreads();
#pragma unroll
    for (int ks = 0; ks < 2; ++ks) {
      bf16x8 af[4], bfr[4];
#pragma unroll
      for (int mf = 0; mf < 4; ++mf) {
        int row = wm + mf * 16 + lr;
        int gc = ks * 4 + lg;
        af[mf] = as_bf16x8(*(const ushort8_t*)&As[row * 64 + ((gc ^ (row & 7)) * 8)]);
      }
#pragma unroll
      for (int nf = 0; nf < 4; ++nf) {
        int row = wn + nf * 16 + lr;
        int gc = ks * 4 + lg;
        bfr[nf] = as_bf16x8(*(const ushort8_t*)&Bs[row * 64 + ((gc ^ (row & 7)) * 8)]);
      }
#pragma unroll
      for (int mf = 0; mf < 4; ++mf)
#pragma unroll
        for (int nf = 0; nf < 4; ++nf) acc[mf][nf] = mfma16(af[mf], bfr[nf], acc[mf][nf]);
    }
    __syncthreads();
  }

#pragma unroll
  for (int nf = 0; nf < 4; ++nf) {
    int n = n0 + wn + nf * 16 + lr;
    float bias = bout[n];
#pragma unroll
    for (int mf = 0; mf < 4; ++mf) {
#pragma unroll
      for (int r = 0; r < 4; ++r) {
        int m = m0 + wm + mf * 16 + lg * 4 + r;
        Y[(size_t)m * 512 + n] = acc[mf][nf][r] + bias + X[(size_t)m * 512 + n];
      }
    }
  }
}

// ---------------- LayerNorm (in place on y region) ----------------
__global__ __launch_bounds__(128) void ln_kernel(
    const float* __restrict__ Z2, const float* __restrict__ gamma,
    const float* __restrict__ beta, float* __restrict__ Y) {
  const int row = blockIdx.x;
  const int t = threadIdx.x;
  float4 v = *(const float4*)(Z2 + (size_t)row * 512 + t * 4);
  float sum = v.x + v.y + v.z + v.w;
  float sq = v.x * v.x + v.y * v.y + v.z * v.z + v.w * v.w;
#pragma unroll
  for (int off = 32; off; off >>= 1) {
    sum += __shfl_xor(sum, off);
    sq += __shfl_xor(sq, off);
  }
  __shared__ float s0[2], s1[2];
  int wv = t >> 6;
  if ((t & 63) == 0) { s0[wv] = sum; s1[wv] = sq; }
  __syncthreads();
  sum = s0[0] + s0[1];
  sq = s1[0] + s1[1];
  float mu = sum * (1.0f / 512.0f);
  float var = sq * (1.0f / 512.0f) - mu * mu;
  float rs = rsqrtf(var + EPSf);
  float4 g = *(const float4*)(gamma + t * 4);
  float4 be = *(const float4*)(beta + t * 4);
  float4 o;
  o.x = (v.x - mu) * rs * g.x + be.x;
  o.y = (v.y - mu) * rs * g.y + be.y;
  o.z = (v.z - mu) * rs * g.z + be.z;
  o.w = (v.w - mu) * rs * g.w + be.w;
  *(float4*)(Y + (size_t)row * 512 + t * 4) = o;
}

extern "C" void kernel_launch(void* const* d_in, const int* in_sizes, int n_in,
                              void* d_out, int out_size, void* d_ws, size_t ws_size,
                              hipStream_t stream) {
  const float* x = (const float*)d_in[0];
  const float* w_in = (const float*)d_in[1];
  const float* b_in = (const float*)d_in[2];
  const float* w_out = (const float*)d_in[3];
  const float* b_out = (const float*)d_in[4];
  const float* gamma = (const float*)d_in[5];
  const float* beta = (const float*)d_in[6];

  float* y = (float*)d_out;                                   // [B,S,E] fp32
  float* att = (float*)d_out + (size_t)Bb * Ss * Ee;          // [B,H,S,S] fp32

  char* ws = (char*)d_ws;
  const size_t NBH = (size_t)Bb * Hh * Ss * Dd;               // 8.39M elems
  unsigned short* Q     = (unsigned short*)ws;                // 16.78 MB
  unsigned short* Kb    = Q + NBH;
  unsigned short* Vb    = Kb + NBH;
  unsigned short* xb    = Vb + NBH;                           // [16384][512] bf16
  unsigned short* Zb    = xb;                                 // alias: xb dead after qkv_mm
  unsigned short* winb  = xb + NBH;                           // [1536][512]
  unsigned short* woutb = winb + (size_t)3 * Ee * Ee;         // [512][512]

  // 1) fp32 -> bf16 converts
  cvt_bf16<<<dim3(1024), 256, 0, stream>>>(x, xb, (int)(NBH / 8));
  cvt_bf16<<<dim3(384), 256, 0, stream>>>(w_in, winb, (int)(3 * Ee * Ee / 8));
  cvt_bf16<<<dim3(128), 256, 0, stream>>>(w_out, woutb, (int)(Ee * Ee / 8));
  // 2) QKV projection (MFMA)
  qkv_mm<<<dim3(12, 128), 256, 0, stream>>>(xb, winb, b_in, Q, Kb, Vb);
  // 3) fused attention: scores + softmax + att store + PV
  attn_fused<<<dim3(8, 256), 256, 0, stream>>>(Q, Kb, Vb, att, Zb);
  // 4) out projection + bias + residual (MFMA)
  out_mm<<<dim3(4, 128), 256, 0, stream>>>(Zb, woutb, b_out, x, y);
  // 5) LayerNorm in place
  ln_kernel<<<dim3(16384), 128, 0, stream>>>(y, gamma, beta, y);
}